// Round 6
// baseline (299.061 us; speedup 1.0000x reference)
//
#include <hip/hip_runtime.h>
#include <hip/hip_bf16.h>
#include <stdint.h>

typedef __bf16 bf16x8 __attribute__((ext_vector_type(8)));
typedef float  f32x4  __attribute__((ext_vector_type(4)));
typedef __hip_bfloat16 bf16_t;

#define D_MODEL 1024
#define NH 16
#define DH 64
#define BB 2
#define SS 2048
#define MTOT (BB*SS)   /* 4096 */
#define NQT (SS/64)    /* 32 q-tiles per (b,h) */

#define GBM 128
#define GBN 128
#define GBK 64

// ---------------------------------------------------------------------------
// fp32 -> bf16 convert for q,k,v (one launch, 3 tensors)
// ---------------------------------------------------------------------------
__global__ void cvt_qkv_kernel(const float* __restrict__ q, const float* __restrict__ k,
                               const float* __restrict__ v, bf16_t* __restrict__ dst) {
  const int n1v = MTOT * D_MODEL / 4;  // float4 count per tensor
  int tid = blockIdx.x * blockDim.x + threadIdx.x;
  int stride = gridDim.x * blockDim.x;
  for (int i = tid; i < 3 * n1v; i += stride) {
    int which = i / n1v;
    int j = i - which * n1v;
    const float4* src = (const float4*)(which == 0 ? q : (which == 1 ? k : v));
    float4 f = src[j];
    union { bf16_t h[4]; short4 s4; } u;
    u.h[0] = __float2bfloat16(f.x);
    u.h[1] = __float2bfloat16(f.y);
    u.h[2] = __float2bfloat16(f.z);
    u.h[3] = __float2bfloat16(f.w);
    ((short4*)dst)[(size_t)which * n1v + j] = u.s4;
  }
}

// ---------------------------------------------------------------------------
// W [K][N] fp32  ->  Wt [N][K] bf16   (z = 0..3 selects Wq,Wk,Wv,Wo)
// ---------------------------------------------------------------------------
__global__ void transpose_w_kernel(const float* __restrict__ W0, const float* __restrict__ W1,
                                   const float* __restrict__ W2, const float* __restrict__ W3,
                                   bf16_t* __restrict__ WtAll) {
  __shared__ float tile[32][33];
  const int z = blockIdx.z;
  const float* W = (z == 0) ? W0 : (z == 1) ? W1 : (z == 2) ? W2 : W3;
  bf16_t* Wt = WtAll + (size_t)z * D_MODEL * D_MODEL;
  const int tx = threadIdx.x, ty = threadIdx.y;
  const int bx = blockIdx.x, by = blockIdx.y;
#pragma unroll
  for (int i = 0; i < 4; ++i)
    tile[ty + i * 8][tx] = W[(size_t)(by * 32 + ty + i * 8) * D_MODEL + bx * 32 + tx];
  __syncthreads();
#pragma unroll
  for (int i = 0; i < 4; ++i)
    Wt[(size_t)(bx * 32 + ty + i * 8) * D_MODEL + by * 32 + tx] =
        __float2bfloat16(tile[tx][ty + i * 8]);
}

// ---------------------------------------------------------------------------
// GEMM mainloop: C[128x128] tile, A [M][K] bf16 row-major, Bt [N][K] bf16.
// 256 threads = 4 waves (2x2), each wave 64x64 = 4x4 frags of 16x16.
// global_load_lds width-16 staging, single-buffered (m97 structure).
// ---------------------------------------------------------------------------
__device__ __forceinline__ void g2lds16(const bf16_t* g, bf16_t* l) {
  __builtin_amdgcn_global_load_lds((__attribute__((address_space(1))) void*)(g),
                                   (__attribute__((address_space(3))) void*)(l), 16, 0, 0);
}

__device__ __forceinline__ void gemm_tile_mainloop(const bf16_t* __restrict__ A,
                                                   const bf16_t* __restrict__ Bt,
                                                   bf16_t* As, bf16_t* Bs,
                                                   int m0, int n0, f32x4 acc[4][4]) {
  const int tid = threadIdx.x;
  const int wv = tid >> 6, ln = tid & 63;
  const int wr = wv >> 1, wc = wv & 1;
  const int lr = ln & 15, lg = ln >> 4;

#pragma unroll
  for (int mi = 0; mi < 4; ++mi)
#pragma unroll
    for (int ni = 0; ni < 4; ++ni)
      acc[mi][ni] = (f32x4){0.f, 0.f, 0.f, 0.f};

  for (int kt = 0; kt < D_MODEL / GBK; ++kt) {
    // stage A and B tiles: each wave issues 4+4 1KB direct-to-LDS loads
#pragma unroll
    for (int c = 0; c < 4; ++c) {
      int chunk = wv * 4 + c;
      int row = chunk * 8 + (ln >> 3);
      int col = (ln & 7) * 8;
      g2lds16(A  + (size_t)(m0 + row) * D_MODEL + kt * GBK + col, As + chunk * 8 * GBK);
      g2lds16(Bt + (size_t)(n0 + row) * D_MODEL + kt * GBK + col, Bs + chunk * 8 * GBK);
    }
    __syncthreads();
#pragma unroll
    for (int ks = 0; ks < 2; ++ks) {
      bf16x8 af[4], bfr[4];
#pragma unroll
      for (int mi = 0; mi < 4; ++mi)
        af[mi] = *(const bf16x8*)(As + (size_t)(wr * 64 + mi * 16 + lr) * GBK + ks * 32 + lg * 8);
#pragma unroll
      for (int ni = 0; ni < 4; ++ni)
        bfr[ni] = *(const bf16x8*)(Bs + (size_t)(wc * 64 + ni * 16 + lr) * GBK + ks * 32 + lg * 8);
#pragma unroll
      for (int mi = 0; mi < 4; ++mi)
#pragma unroll
        for (int ni = 0; ni < 4; ++ni)
          acc[mi][ni] = __builtin_amdgcn_mfma_f32_16x16x32_bf16(af[mi], bfr[ni], acc[mi][ni], 0, 0, 0);
    }
    __syncthreads();
  }
}

// ---------------------------------------------------------------------------
// Projection GEMM: z=0 -> Q (bf16 [M][N]), z=1 -> K (bf16 [M][N]),
// z=2 -> V written transposed as Vt[(b*1024 + n)][s]  (bf16)
// ---------------------------------------------------------------------------
__global__ __launch_bounds__(256)
void proj_gemm_kernel(const bf16_t* __restrict__ Aq, const bf16_t* __restrict__ Ak,
                      const bf16_t* __restrict__ Av, const bf16_t* __restrict__ WtAll,
                      const float* __restrict__ bq, const float* __restrict__ bk,
                      const float* __restrict__ bv,
                      bf16_t* __restrict__ Qg, bf16_t* __restrict__ Kg,
                      bf16_t* __restrict__ Vt) {
  __shared__ bf16_t As[GBM * GBK];
  __shared__ bf16_t Bs[GBN * GBK];
  const int z = blockIdx.z;
  const bf16_t* A = (z == 0) ? Aq : (z == 1) ? Ak : Av;
  const bf16_t* Bt = WtAll + (size_t)z * D_MODEL * D_MODEL;
  const float* bias = (z == 0) ? bq : (z == 1) ? bk : bv;
  const int m0 = blockIdx.y * GBM, n0 = blockIdx.x * GBN;

  f32x4 acc[4][4];
  gemm_tile_mainloop(A, Bt, As, Bs, m0, n0, acc);

  const int tid = threadIdx.x;
  const int wv = tid >> 6, ln = tid & 63;
  const int wr = wv >> 1, wc = wv & 1;
  const int lr = ln & 15, lg = ln >> 4;

#pragma unroll
  for (int mi = 0; mi < 4; ++mi) {
#pragma unroll
    for (int ni = 0; ni < 4; ++ni) {
      int ncol = n0 + wc * 64 + ni * 16 + lr;
      float bsv = bias[ncol];
#pragma unroll
      for (int j = 0; j < 4; ++j) {
        int mrow = m0 + wr * 64 + mi * 16 + lg * 4 + j;
        bf16_t hv = __float2bfloat16(acc[mi][ni][j] + bsv);
        if (z == 0) {
          Qg[(size_t)mrow * D_MODEL + ncol] = hv;
        } else if (z == 1) {
          Kg[(size_t)mrow * D_MODEL + ncol] = hv;
        } else {
          int b = mrow >> 11, s = mrow & (SS - 1);
          Vt[(size_t)((b << 10) | ncol) * SS + s] = hv;
        }
      }
    }
  }
}

// ---------------------------------------------------------------------------
// Output GEMM: ctx[M][K] bf16 @ Wo^T [N][K] bf16 + bo -> fp32 out [M][N]
// ---------------------------------------------------------------------------
__global__ __launch_bounds__(256)
void out_gemm_kernel(const bf16_t* __restrict__ Ctx, const bf16_t* __restrict__ Wto,
                     const float* __restrict__ bo, float* __restrict__ out) {
  __shared__ bf16_t As[GBM * GBK];
  __shared__ bf16_t Bs[GBN * GBK];
  const int m0 = blockIdx.y * GBM, n0 = blockIdx.x * GBN;

  f32x4 acc[4][4];
  gemm_tile_mainloop(Ctx, Wto, As, Bs, m0, n0, acc);

  const int tid = threadIdx.x;
  const int wv = tid >> 6, ln = tid & 63;
  const int wr = wv >> 1, wc = wv & 1;
  const int lr = ln & 15, lg = ln >> 4;

#pragma unroll
  for (int mi = 0; mi < 4; ++mi) {
#pragma unroll
    for (int ni = 0; ni < 4; ++ni) {
      int ncol = n0 + wc * 64 + ni * 16 + lr;
      float bsv = bo[ncol];
#pragma unroll
      for (int j = 0; j < 4; ++j) {
        int mrow = m0 + wr * 64 + mi * 16 + lg * 4 + j;
        out[(size_t)mrow * D_MODEL + ncol] = acc[mi][ni][j] + bsv;
      }
    }
  }
}

// ---------------------------------------------------------------------------
// Flash attention, causal. Block = 128 threads (2 waves), each wave 32 q-rows.
// CAUSAL PAIRING for load balance: block (bh, p) processes q-tiles p and
// NQT-1-p sequentially -> every block does exactly NQT+1 = 33 tile-units.
// (R5 profile: whole grid co-resident; duration was set by straggler blocks
// with 32 tiles; occupancy decayed 25%->0. Pairing flattens it.)
// Register-prefetch K(t+1)/V(t); row-sum via MFMA ones-fragment; setprio
// around MFMA clusters.
// ---------------------------------------------------------------------------
__global__ __launch_bounds__(128)
void attn_kernel(const bf16_t* __restrict__ Qg, const bf16_t* __restrict__ Kg,
                 const bf16_t* __restrict__ Vt, bf16_t* __restrict__ Ctx) {
  __shared__ __align__(16) bf16_t P_lds[2][32][72];  // +8 pad: 2-way-free reads
  const int bh = blockIdx.x;
  const int pr = blockIdx.y;
  const int b = bh >> 4, h = bh & 15;
  const int wv = threadIdx.x >> 6, ln = threadIdx.x & 63;
  const int lr = ln & 15, lg = ln >> 4;

  const size_t qkbase = (size_t)b * SS * D_MODEL + (size_t)h * DH;
  const bf16_t* Kbase = Kg + qkbase;
  const bf16_t* Vbase = Vt + (size_t)(bh * 64) * SS;

  bf16x8 onesf;
#pragma unroll
  for (int j = 0; j < 8; ++j) onesf[j] = (__bf16)1.0f;

  for (int half = 0; half < 2; ++half) {
    const int qt = half ? (NQT - 1 - pr) : pr;
    const int q0 = qt * 64 + wv * 32;

    // Q fragments, scale 1/8 folded in (exact in bf16: exponent-only)
    bf16x8 qf[2][2];
#pragma unroll
    for (int mi = 0; mi < 2; ++mi)
#pragma unroll
      for (int ks = 0; ks < 2; ++ks) {
        bf16x8 raw = *(const bf16x8*)(Qg + qkbase + (size_t)(q0 + mi * 16 + lr) * D_MODEL + ks * 32 + lg * 8);
#pragma unroll
        for (int j = 0; j < 8; ++j) raw[j] = (__bf16)((float)raw[j] * 0.125f);
        qf[mi][ks] = raw;
      }

    f32x4 acc_o[2][4];
    f32x4 acc_l[2];
    float m_run[2][4];
#pragma unroll
    for (int mi = 0; mi < 2; ++mi) {
#pragma unroll
      for (int db = 0; db < 4; ++db) acc_o[mi][db] = (f32x4){0.f, 0.f, 0.f, 0.f};
      acc_l[mi] = (f32x4){0.f, 0.f, 0.f, 0.f};
#pragma unroll
      for (int j = 0; j < 4; ++j) m_run[mi][j] = -1e30f;
    }

    // prologue: K fragments for tile 0
    bf16x8 kf_cur[2][4];
#pragma unroll
    for (int ks = 0; ks < 2; ++ks)
#pragma unroll
      for (int kb = 0; kb < 4; ++kb)
        kf_cur[ks][kb] = *(const bf16x8*)(Kbase + (size_t)(kb * 16 + lr) * D_MODEL + ks * 32 + lg * 8);

    const int ntiles = qt + 1;
    for (int t = 0; t < ntiles; ++t) {
      const int kv0 = t * 64;
      f32x4 sc[2][4];
#pragma unroll
      for (int mi = 0; mi < 2; ++mi)
#pragma unroll
        for (int kb = 0; kb < 4; ++kb) sc[mi][kb] = (f32x4){0.f, 0.f, 0.f, 0.f};

      // S = Q K^T (scaled)
      __builtin_amdgcn_s_setprio(1);
#pragma unroll
      for (int ks = 0; ks < 2; ++ks) {
#pragma unroll
        for (int kb = 0; kb < 4; ++kb) {
          sc[0][kb] = __builtin_amdgcn_mfma_f32_16x16x32_bf16(qf[0][ks], kf_cur[ks][kb], sc[0][kb], 0, 0, 0);
          sc[1][kb] = __builtin_amdgcn_mfma_f32_16x16x32_bf16(qf[1][ks], kf_cur[ks][kb], sc[1][kb], 0, 0, 0);
        }
      }
      __builtin_amdgcn_s_setprio(0);

      // prefetch K(t+1): consumed ~softmax+PV later, fully hidden
      bf16x8 kf_nxt[2][4];
      if (t + 1 < ntiles) {
#pragma unroll
        for (int ks = 0; ks < 2; ++ks)
#pragma unroll
          for (int kb = 0; kb < 4; ++kb)
            kf_nxt[ks][kb] = *(const bf16x8*)(Kbase + (size_t)(kv0 + 64 + kb * 16 + lr) * D_MODEL + ks * 32 + lg * 8);
      }
      // prefetch V(t): consumed after softmax, hidden under the exp chain
      bf16x8 vf[2][4];
#pragma unroll
      for (int ks = 0; ks < 2; ++ks)
#pragma unroll
        for (int db = 0; db < 4; ++db)
          vf[ks][db] = *(const bf16x8*)(Vbase + (size_t)(db * 16 + lr) * SS + kv0 + ks * 32 + lg * 8);

      // causal mask (only diagonal-crossing tiles; wave-uniform test)
      if (kv0 + 63 > q0) {
#pragma unroll
        for (int mi = 0; mi < 2; ++mi)
#pragma unroll
          for (int kb = 0; kb < 4; ++kb)
#pragma unroll
            for (int j = 0; j < 4; ++j) {
              int kc = kv0 + kb * 16 + lr;
              int qr = q0 + mi * 16 + lg * 4 + j;
              if (kc > qr) sc[mi][kb][j] = -1e30f;
            }
      }

      // online softmax: row max via 4-step shuffle; row sum via MFMA later
#pragma unroll
      for (int mi = 0; mi < 2; ++mi) {
#pragma unroll
        for (int j = 0; j < 4; ++j) {
          float vmax = fmaxf(fmaxf(sc[mi][0][j], sc[mi][1][j]), fmaxf(sc[mi][2][j], sc[mi][3][j]));
#pragma unroll
          for (int off = 1; off < 16; off <<= 1) vmax = fmaxf(vmax, __shfl_xor(vmax, off, 64));
          float mo = m_run[mi][j];
          float mn = fmaxf(mo, vmax);
          float scl = __expf(mo - mn);
          m_run[mi][j] = mn;
#pragma unroll
          for (int kb = 0; kb < 4; ++kb) {
            float p = __expf(sc[mi][kb][j] - mn);
            P_lds[wv][mi * 16 + lg * 4 + j][kb * 16 + lr] = __float2bfloat16(p);
          }
          acc_l[mi][j] *= scl;
#pragma unroll
          for (int db = 0; db < 4; ++db) acc_o[mi][db][j] *= scl;
        }
      }

      // wave-internal LDS visibility (per-wave region, no barrier needed).
      // sched_barrier(0) per guide rule #18: prevent MFMA hoisting past the wait.
      asm volatile("s_waitcnt lgkmcnt(0)" ::: "memory");
      __builtin_amdgcn_sched_barrier(0);

      // O += P V ; l += P * 1 (row-sum via MFMA, replicated across cols)
      __builtin_amdgcn_s_setprio(1);
#pragma unroll
      for (int ks = 0; ks < 2; ++ks) {
        bf16x8 pa0 = *(const bf16x8*)(&P_lds[wv][lr][ks * 32 + lg * 8]);
        bf16x8 pa1 = *(const bf16x8*)(&P_lds[wv][16 + lr][ks * 32 + lg * 8]);
        acc_l[0] = __builtin_amdgcn_mfma_f32_16x16x32_bf16(pa0, onesf, acc_l[0], 0, 0, 0);
        acc_l[1] = __builtin_amdgcn_mfma_f32_16x16x32_bf16(pa1, onesf, acc_l[1], 0, 0, 0);
#pragma unroll
        for (int db = 0; db < 4; ++db) {
          acc_o[0][db] = __builtin_amdgcn_mfma_f32_16x16x32_bf16(pa0, vf[ks][db], acc_o[0][db], 0, 0, 0);
          acc_o[1][db] = __builtin_amdgcn_mfma_f32_16x16x32_bf16(pa1, vf[ks][db], acc_o[1][db], 0, 0, 0);
        }
      }
      __builtin_amdgcn_s_setprio(0);

      if (t + 1 < ntiles) {
#pragma unroll
        for (int ks = 0; ks < 2; ++ks)
#pragma unroll
          for (int kb = 0; kb < 4; ++kb)
            kf_cur[ks][kb] = kf_nxt[ks][kb];
      }
    }

    // epilogue: ctx = O / l, bf16 row-major [B*S][D_MODEL]
#pragma unroll
    for (int mi = 0; mi < 2; ++mi)
#pragma unroll
      for (int db = 0; db < 4; ++db)
#pragma unroll
        for (int j = 0; j < 4; ++j) {
          int qr = q0 + mi * 16 + lg * 4 + j;
          float val = acc_o[mi][db][j] / acc_l[mi][j];
          Ctx[(size_t)(b * SS + qr) * D_MODEL + h * DH + db * 16 + lr] = __float2bfloat16(val);
        }
  }
}

// ---------------------------------------------------------------------------
extern "C" void kernel_launch(void* const* d_in, const int* in_sizes, int n_in,
                              void* d_out, int out_size, void* d_ws, size_t ws_size,
                              hipStream_t stream) {
  const float* q  = (const float*)d_in[0];
  const float* k  = (const float*)d_in[1];
  const float* v  = (const float*)d_in[2];
  // d_in[3] = additive causal mask — applied analytically in attn_kernel
  const float* bq = (const float*)d_in[5];
  const float* bk = (const float*)d_in[7];
  const float* bv = (const float*)d_in[9];
  const float* bo = (const float*)d_in[11];
  const float* Wq = (const float*)d_in[4];
  const float* Wk = (const float*)d_in[6];
  const float* Wv = (const float*)d_in[8];
  const float* Wo = (const float*)d_in[10];
  float* out = (float*)d_out;

  char* w = (char*)d_ws;
  bf16_t* Aqkv  = (bf16_t*)(w);                       // 3 x [4096][1024] bf16
  bf16_t* WtAll = (bf16_t*)(w + 25165824);            // 4 x [1024][1024] bf16
  bf16_t* Qg    = (bf16_t*)(w + 33554432);            // [4096][1024] bf16
  bf16_t* Kg    = (bf16_t*)(w + 41943040);            // [4096][1024] bf16
  bf16_t* Vt    = (bf16_t*)(w + 50331648);            // [2048][2048] bf16 (per-b, n-major)
  bf16_t* Ctx   = (bf16_t*)(w + 58720256);            // [4096][1024] bf16

  cvt_qkv_kernel<<<2048, 256, 0, stream>>>(q, k, v, Aqkv);
  transpose_w_kernel<<<dim3(32, 32, 4), dim3(32, 8), 0, stream>>>(Wq, Wk, Wv, Wo, WtAll);
  proj_gemm_kernel<<<dim3(8, 32, 3), 256, 0, stream>>>(
      Aqkv, Aqkv + (size_t)MTOT * D_MODEL, Aqkv + 2 * (size_t)MTOT * D_MODEL,
      WtAll, bq, bk, bv, Qg, Kg, Vt);
  attn_kernel<<<dim3(32, 16), 128, 0, stream>>>(Qg, Kg, Vt, Ctx);
  out_gemm_kernel<<<dim3(8, 32), 256, 0, stream>>>(
      Ctx, WtAll + 3 * (size_t)D_MODEL * D_MODEL, bo, out);
}

// Round 7
// 295.063 us; speedup vs baseline: 1.0136x; 1.0136x over previous
//
#include <hip/hip_runtime.h>
#include <hip/hip_bf16.h>
#include <stdint.h>

typedef __bf16 bf16x8 __attribute__((ext_vector_type(8)));
typedef float  f32x4  __attribute__((ext_vector_type(4)));
typedef __hip_bfloat16 bf16_t;

#define D_MODEL 1024
#define NH 16
#define DH 64
#define BB 2
#define SS 2048
#define MTOT (BB*SS)   /* 4096 */
#define NQT (SS/64)    /* 32 q-tiles per (b,h) */

#define GBM 128
#define GBN 128
#define GBK 64

// ---------------------------------------------------------------------------
// fp32 -> bf16 convert for q,k,v (one launch, 3 tensors)
// ---------------------------------------------------------------------------
__global__ void cvt_qkv_kernel(const float* __restrict__ q, const float* __restrict__ k,
                               const float* __restrict__ v, bf16_t* __restrict__ dst) {
  const int n1v = MTOT * D_MODEL / 4;  // float4 count per tensor
  int tid = blockIdx.x * blockDim.x + threadIdx.x;
  int stride = gridDim.x * blockDim.x;
  for (int i = tid; i < 3 * n1v; i += stride) {
    int which = i / n1v;
    int j = i - which * n1v;
    const float4* src = (const float4*)(which == 0 ? q : (which == 1 ? k : v));
    float4 f = src[j];
    union { bf16_t h[4]; short4 s4; } u;
    u.h[0] = __float2bfloat16(f.x);
    u.h[1] = __float2bfloat16(f.y);
    u.h[2] = __float2bfloat16(f.z);
    u.h[3] = __float2bfloat16(f.w);
    ((short4*)dst)[(size_t)which * n1v + j] = u.s4;
  }
}

// ---------------------------------------------------------------------------
// W [K][N] fp32  ->  Wt [N][K] bf16   (z = 0..3 selects Wq,Wk,Wv,Wo)
// ---------------------------------------------------------------------------
__global__ void transpose_w_kernel(const float* __restrict__ W0, const float* __restrict__ W1,
                                   const float* __restrict__ W2, const float* __restrict__ W3,
                                   bf16_t* __restrict__ WtAll) {
  __shared__ float tile[32][33];
  const int z = blockIdx.z;
  const float* W = (z == 0) ? W0 : (z == 1) ? W1 : (z == 2) ? W2 : W3;
  bf16_t* Wt = WtAll + (size_t)z * D_MODEL * D_MODEL;
  const int tx = threadIdx.x, ty = threadIdx.y;
  const int bx = blockIdx.x, by = blockIdx.y;
#pragma unroll
  for (int i = 0; i < 4; ++i)
    tile[ty + i * 8][tx] = W[(size_t)(by * 32 + ty + i * 8) * D_MODEL + bx * 32 + tx];
  __syncthreads();
#pragma unroll
  for (int i = 0; i < 4; ++i)
    Wt[(size_t)(bx * 32 + ty + i * 8) * D_MODEL + by * 32 + tx] =
        __float2bfloat16(tile[tx][ty + i * 8]);
}

// ---------------------------------------------------------------------------
// GEMM mainloop: C[128x128] tile, A [M][K] bf16 row-major, Bt [N][K] bf16.
// 256 threads = 4 waves (2x2), each wave 64x64 = 4x4 frags of 16x16.
// global_load_lds width-16 staging, single-buffered (m97 structure).
// ---------------------------------------------------------------------------
__device__ __forceinline__ void g2lds16(const bf16_t* g, bf16_t* l) {
  __builtin_amdgcn_global_load_lds((__attribute__((address_space(1))) void*)(g),
                                   (__attribute__((address_space(3))) void*)(l), 16, 0, 0);
}

__device__ __forceinline__ void gemm_tile_mainloop(const bf16_t* __restrict__ A,
                                                   const bf16_t* __restrict__ Bt,
                                                   bf16_t* As, bf16_t* Bs,
                                                   int m0, int n0, f32x4 acc[4][4]) {
  const int tid = threadIdx.x;
  const int wv = tid >> 6, ln = tid & 63;
  const int wr = wv >> 1, wc = wv & 1;
  const int lr = ln & 15, lg = ln >> 4;

#pragma unroll
  for (int mi = 0; mi < 4; ++mi)
#pragma unroll
    for (int ni = 0; ni < 4; ++ni)
      acc[mi][ni] = (f32x4){0.f, 0.f, 0.f, 0.f};

  for (int kt = 0; kt < D_MODEL / GBK; ++kt) {
    // stage A and B tiles: each wave issues 4+4 1KB direct-to-LDS loads
#pragma unroll
    for (int c = 0; c < 4; ++c) {
      int chunk = wv * 4 + c;
      int row = chunk * 8 + (ln >> 3);
      int col = (ln & 7) * 8;
      g2lds16(A  + (size_t)(m0 + row) * D_MODEL + kt * GBK + col, As + chunk * 8 * GBK);
      g2lds16(Bt + (size_t)(n0 + row) * D_MODEL + kt * GBK + col, Bs + chunk * 8 * GBK);
    }
    __syncthreads();
#pragma unroll
    for (int ks = 0; ks < 2; ++ks) {
      bf16x8 af[4], bfr[4];
#pragma unroll
      for (int mi = 0; mi < 4; ++mi)
        af[mi] = *(const bf16x8*)(As + (size_t)(wr * 64 + mi * 16 + lr) * GBK + ks * 32 + lg * 8);
#pragma unroll
      for (int ni = 0; ni < 4; ++ni)
        bfr[ni] = *(const bf16x8*)(Bs + (size_t)(wc * 64 + ni * 16 + lr) * GBK + ks * 32 + lg * 8);
#pragma unroll
      for (int mi = 0; mi < 4; ++mi)
#pragma unroll
        for (int ni = 0; ni < 4; ++ni)
          acc[mi][ni] = __builtin_amdgcn_mfma_f32_16x16x32_bf16(af[mi], bfr[ni], acc[mi][ni], 0, 0, 0);
    }
    __syncthreads();
  }
}

// ---------------------------------------------------------------------------
// Projection GEMM: z=0 -> Q (bf16 [M][N]), z=1 -> K (bf16 [M][N]),
// z=2 -> V written transposed as Vt[(b*1024 + n)][s]  (bf16)
// ---------------------------------------------------------------------------
__global__ __launch_bounds__(256)
void proj_gemm_kernel(const bf16_t* __restrict__ Aq, const bf16_t* __restrict__ Ak,
                      const bf16_t* __restrict__ Av, const bf16_t* __restrict__ WtAll,
                      const float* __restrict__ bq, const float* __restrict__ bk,
                      const float* __restrict__ bv,
                      bf16_t* __restrict__ Qg, bf16_t* __restrict__ Kg,
                      bf16_t* __restrict__ Vt) {
  __shared__ bf16_t As[GBM * GBK];
  __shared__ bf16_t Bs[GBN * GBK];
  const int z = blockIdx.z;
  const bf16_t* A = (z == 0) ? Aq : (z == 1) ? Ak : Av;
  const bf16_t* Bt = WtAll + (size_t)z * D_MODEL * D_MODEL;
  const float* bias = (z == 0) ? bq : (z == 1) ? bk : bv;
  const int m0 = blockIdx.y * GBM, n0 = blockIdx.x * GBN;

  f32x4 acc[4][4];
  gemm_tile_mainloop(A, Bt, As, Bs, m0, n0, acc);

  const int tid = threadIdx.x;
  const int wv = tid >> 6, ln = tid & 63;
  const int wr = wv >> 1, wc = wv & 1;
  const int lr = ln & 15, lg = ln >> 4;

#pragma unroll
  for (int mi = 0; mi < 4; ++mi) {
#pragma unroll
    for (int ni = 0; ni < 4; ++ni) {
      int ncol = n0 + wc * 64 + ni * 16 + lr;
      float bsv = bias[ncol];
#pragma unroll
      for (int j = 0; j < 4; ++j) {
        int mrow = m0 + wr * 64 + mi * 16 + lg * 4 + j;
        bf16_t hv = __float2bfloat16(acc[mi][ni][j] + bsv);
        if (z == 0) {
          Qg[(size_t)mrow * D_MODEL + ncol] = hv;
        } else if (z == 1) {
          Kg[(size_t)mrow * D_MODEL + ncol] = hv;
        } else {
          int b = mrow >> 11, s = mrow & (SS - 1);
          Vt[(size_t)((b << 10) | ncol) * SS + s] = hv;
        }
      }
    }
  }
}

// ---------------------------------------------------------------------------
// Output GEMM: ctx[M][K] bf16 @ Wo^T [N][K] bf16 + bo -> fp32 out [M][N]
// ---------------------------------------------------------------------------
__global__ __launch_bounds__(256)
void out_gemm_kernel(const bf16_t* __restrict__ Ctx, const bf16_t* __restrict__ Wto,
                     const float* __restrict__ bo, float* __restrict__ out) {
  __shared__ bf16_t As[GBM * GBK];
  __shared__ bf16_t Bs[GBN * GBK];
  const int m0 = blockIdx.y * GBM, n0 = blockIdx.x * GBN;

  f32x4 acc[4][4];
  gemm_tile_mainloop(Ctx, Wto, As, Bs, m0, n0, acc);

  const int tid = threadIdx.x;
  const int wv = tid >> 6, ln = tid & 63;
  const int wr = wv >> 1, wc = wv & 1;
  const int lr = ln & 15, lg = ln >> 4;

#pragma unroll
  for (int mi = 0; mi < 4; ++mi) {
#pragma unroll
    for (int ni = 0; ni < 4; ++ni) {
      int ncol = n0 + wc * 64 + ni * 16 + lr;
      float bsv = bo[ncol];
#pragma unroll
      for (int j = 0; j < 4; ++j) {
        int mrow = m0 + wr * 64 + mi * 16 + lg * 4 + j;
        out[(size_t)mrow * D_MODEL + ncol] = acc[mi][ni][j] + bsv;
      }
    }
  }
}

// ---------------------------------------------------------------------------
// Flash attention, causal. Block = 256 threads (4 waves), grid (bh, pp).
// Pair (qt=pp, qt=NQT-1-pp) for balance; split-KV inside the block so every
// wave gets 16-17 KV-tile-units flat (R6 lesson: 33-unit serial path at
// 1 wave/SIMD was the bound). Waves 0,1: low tile (full, store direct) +
// high tile KV[0,16-pp). Waves 2,3: high tile KV[16-pp,32-pp) incl diag,
// partial (O,m,l) -> LDS. One __syncthreads, waves 0,1 merge + store.
// 2048 waves total = 2 waves/SIMD flat.
// ---------------------------------------------------------------------------
__device__ __forceinline__ void attn_run(
    f32x4 acc_o[2][4], f32x4 acc_l[2], float m_run[2][4],
    const bf16x8 qf[2][2], const bf16_t* Kbase, const bf16_t* Vbase,
    bf16_t (*P)[72], int q0, int t0, int t1, int lr, int lg, bf16x8 onesf) {
  // prologue: K fragments for first tile
  bf16x8 kf_cur[2][4];
#pragma unroll
  for (int ks = 0; ks < 2; ++ks)
#pragma unroll
    for (int kb = 0; kb < 4; ++kb)
      kf_cur[ks][kb] = *(const bf16x8*)(Kbase + (size_t)(t0 * 64 + kb * 16 + lr) * D_MODEL + ks * 32 + lg * 8);

  for (int t = t0; t < t1; ++t) {
    const int kv0 = t * 64;
    f32x4 sc[2][4];
#pragma unroll
    for (int mi = 0; mi < 2; ++mi)
#pragma unroll
      for (int kb = 0; kb < 4; ++kb) sc[mi][kb] = (f32x4){0.f, 0.f, 0.f, 0.f};

    // S = Q K^T (scaled)
    __builtin_amdgcn_s_setprio(1);
#pragma unroll
    for (int ks = 0; ks < 2; ++ks) {
#pragma unroll
      for (int kb = 0; kb < 4; ++kb) {
        sc[0][kb] = __builtin_amdgcn_mfma_f32_16x16x32_bf16(qf[0][ks], kf_cur[ks][kb], sc[0][kb], 0, 0, 0);
        sc[1][kb] = __builtin_amdgcn_mfma_f32_16x16x32_bf16(qf[1][ks], kf_cur[ks][kb], sc[1][kb], 0, 0, 0);
      }
    }
    __builtin_amdgcn_s_setprio(0);

    // prefetch K(t+1)
    bf16x8 kf_nxt[2][4];
    if (t + 1 < t1) {
#pragma unroll
      for (int ks = 0; ks < 2; ++ks)
#pragma unroll
        for (int kb = 0; kb < 4; ++kb)
          kf_nxt[ks][kb] = *(const bf16x8*)(Kbase + (size_t)(kv0 + 64 + kb * 16 + lr) * D_MODEL + ks * 32 + lg * 8);
    }
    // prefetch V(t)
    bf16x8 vf[2][4];
#pragma unroll
    for (int ks = 0; ks < 2; ++ks)
#pragma unroll
      for (int db = 0; db < 4; ++db)
        vf[ks][db] = *(const bf16x8*)(Vbase + (size_t)(db * 16 + lr) * SS + kv0 + ks * 32 + lg * 8);

    // causal mask (only diagonal-crossing tiles; wave-uniform test)
    if (kv0 + 63 > q0) {
#pragma unroll
      for (int mi = 0; mi < 2; ++mi)
#pragma unroll
        for (int kb = 0; kb < 4; ++kb)
#pragma unroll
          for (int j = 0; j < 4; ++j) {
            int kc = kv0 + kb * 16 + lr;
            int qr = q0 + mi * 16 + lg * 4 + j;
            if (kc > qr) sc[mi][kb][j] = -1e30f;
          }
    }

    // online softmax: row max via 4-step shuffle; row sum via MFMA later
#pragma unroll
    for (int mi = 0; mi < 2; ++mi) {
#pragma unroll
      for (int j = 0; j < 4; ++j) {
        float vmax = fmaxf(fmaxf(sc[mi][0][j], sc[mi][1][j]), fmaxf(sc[mi][2][j], sc[mi][3][j]));
#pragma unroll
        for (int off = 1; off < 16; off <<= 1) vmax = fmaxf(vmax, __shfl_xor(vmax, off, 64));
        float mo = m_run[mi][j];
        float mn = fmaxf(mo, vmax);
        float scl = __expf(mo - mn);
        m_run[mi][j] = mn;
#pragma unroll
        for (int kb = 0; kb < 4; ++kb) {
          float p = __expf(sc[mi][kb][j] - mn);
          P[mi * 16 + lg * 4 + j][kb * 16 + lr] = __float2bfloat16(p);
        }
        acc_l[mi][j] *= scl;
#pragma unroll
        for (int db = 0; db < 4; ++db) acc_o[mi][db][j] *= scl;
      }
    }

    // wave-internal LDS visibility (per-wave region, no barrier needed).
    asm volatile("s_waitcnt lgkmcnt(0)" ::: "memory");
    __builtin_amdgcn_sched_barrier(0);

    // O += P V ; l += P * 1 (row-sum via MFMA, replicated across cols)
    __builtin_amdgcn_s_setprio(1);
#pragma unroll
    for (int ks = 0; ks < 2; ++ks) {
      bf16x8 pa0 = *(const bf16x8*)(&P[lr][ks * 32 + lg * 8]);
      bf16x8 pa1 = *(const bf16x8*)(&P[16 + lr][ks * 32 + lg * 8]);
      acc_l[0] = __builtin_amdgcn_mfma_f32_16x16x32_bf16(pa0, onesf, acc_l[0], 0, 0, 0);
      acc_l[1] = __builtin_amdgcn_mfma_f32_16x16x32_bf16(pa1, onesf, acc_l[1], 0, 0, 0);
#pragma unroll
      for (int db = 0; db < 4; ++db) {
        acc_o[0][db] = __builtin_amdgcn_mfma_f32_16x16x32_bf16(pa0, vf[ks][db], acc_o[0][db], 0, 0, 0);
        acc_o[1][db] = __builtin_amdgcn_mfma_f32_16x16x32_bf16(pa1, vf[ks][db], acc_o[1][db], 0, 0, 0);
      }
    }
    __builtin_amdgcn_s_setprio(0);

    if (t + 1 < t1) {
#pragma unroll
      for (int ks = 0; ks < 2; ++ks)
#pragma unroll
        for (int kb = 0; kb < 4; ++kb)
          kf_cur[ks][kb] = kf_nxt[ks][kb];
    }
  }
}

__device__ __forceinline__ void attn_load_q(bf16x8 qf[2][2], const bf16_t* Qbase,
                                            int q0, int lr, int lg) {
#pragma unroll
  for (int mi = 0; mi < 2; ++mi)
#pragma unroll
    for (int ks = 0; ks < 2; ++ks) {
      bf16x8 raw = *(const bf16x8*)(Qbase + (size_t)(q0 + mi * 16 + lr) * D_MODEL + ks * 32 + lg * 8);
#pragma unroll
      for (int j = 0; j < 8; ++j) raw[j] = (__bf16)((float)raw[j] * 0.125f);
      qf[mi][ks] = raw;
    }
}

__device__ __forceinline__ void attn_init(f32x4 acc_o[2][4], f32x4 acc_l[2], float m_run[2][4]) {
#pragma unroll
  for (int mi = 0; mi < 2; ++mi) {
#pragma unroll
    for (int db = 0; db < 4; ++db) acc_o[mi][db] = (f32x4){0.f, 0.f, 0.f, 0.f};
    acc_l[mi] = (f32x4){0.f, 0.f, 0.f, 0.f};
#pragma unroll
    for (int j = 0; j < 4; ++j) m_run[mi][j] = -1e30f;
  }
}

__global__ __launch_bounds__(256)
void attn_kernel(const bf16_t* __restrict__ Qg, const bf16_t* __restrict__ Kg,
                 const bf16_t* __restrict__ Vt, bf16_t* __restrict__ Ctx) {
  __shared__ __align__(16) bf16_t P_lds[4][32][72];
  __shared__ __align__(16) float  O_part[2][32][68];   // waves 2,3 partial O (+pad)
  __shared__ float  ml_part[2][32][2];                 // [row][0]=m, [1]=l
  const int bh = blockIdx.x;
  const int pp = blockIdx.y;
  const int b = bh >> 4, h = bh & 15;
  const int wv = threadIdx.x >> 6, ln = threadIdx.x & 63;
  const int lr = ln & 15, lg = ln >> 4;

  const int qt_lo = pp, qt_hi = NQT - 1 - pp;
  const int h0 = 16 - pp;                 // high tile KV split point
  const int rh = wv & 1;                  // row half within the 64-row tile

  const size_t qkbase = (size_t)b * SS * D_MODEL + (size_t)h * DH;
  const bf16_t* Qbase = Qg + qkbase;
  const bf16_t* Kbase = Kg + qkbase;
  const bf16_t* Vbase = Vt + (size_t)(bh * 64) * SS;

  bf16x8 onesf;
#pragma unroll
  for (int j = 0; j < 8; ++j) onesf[j] = (__bf16)1.0f;

  bf16x8 qf[2][2];
  f32x4 acc_o[2][4];
  f32x4 acc_l[2];
  float m_run[2][4];
  const int q0_hi = qt_hi * 64 + rh * 32;

  if (wv < 2) {
    // ---- low tile, full KV range [0, pp+1), direct store ----
    const int q0_lo = qt_lo * 64 + rh * 32;
    attn_load_q(qf, Qbase, q0_lo, lr, lg);
    attn_init(acc_o, acc_l, m_run);
    attn_run(acc_o, acc_l, m_run, qf, Kbase, Vbase, P_lds[wv], q0_lo, 0, pp + 1, lr, lg, onesf);
#pragma unroll
    for (int mi = 0; mi < 2; ++mi)
#pragma unroll
      for (int db = 0; db < 4; ++db)
#pragma unroll
        for (int j = 0; j < 4; ++j) {
          int qr = q0_lo + mi * 16 + lg * 4 + j;
          float val = acc_o[mi][db][j] / acc_l[mi][j];
          Ctx[(size_t)(b * SS + qr) * D_MODEL + h * DH + db * 16 + lr] = __float2bfloat16(val);
        }

    // ---- high tile part A: KV [0, h0), keep in regs for merge ----
    attn_load_q(qf, Qbase, q0_hi, lr, lg);
    attn_init(acc_o, acc_l, m_run);
    attn_run(acc_o, acc_l, m_run, qf, Kbase, Vbase, P_lds[wv], q0_hi, 0, h0, lr, lg, onesf);
  } else {
    // ---- high tile part B: KV [h0, 32-pp) incl. diagonal ----
    attn_load_q(qf, Qbase, q0_hi, lr, lg);
    attn_init(acc_o, acc_l, m_run);
    attn_run(acc_o, acc_l, m_run, qf, Kbase, Vbase, P_lds[wv], q0_hi, h0, NQT - pp, lr, lg, onesf);
    // dump partial (O, m, l) to LDS
    const int pidx = wv - 2;
#pragma unroll
    for (int mi = 0; mi < 2; ++mi)
#pragma unroll
      for (int j = 0; j < 4; ++j) {
        int r = mi * 16 + lg * 4 + j;
#pragma unroll
        for (int db = 0; db < 4; ++db)
          O_part[pidx][r][db * 16 + lr] = acc_o[mi][db][j];
        if (lr == 0) {
          ml_part[pidx][r][0] = m_run[mi][j];
          ml_part[pidx][r][1] = acc_l[mi][j];
        }
      }
  }

  __syncthreads();

  if (wv < 2) {
    // ---- merge part A (regs) with part B (LDS) and store high tile ----
#pragma unroll
    for (int mi = 0; mi < 2; ++mi)
#pragma unroll
      for (int j = 0; j < 4; ++j) {
        int r = mi * 16 + lg * 4 + j;
        float m1 = m_run[mi][j];
        float m2 = ml_part[wv][r][0];
        float mn = fmaxf(m1, m2);
        float a1 = __expf(m1 - mn);
        float a2 = __expf(m2 - mn);
        float l = a1 * acc_l[mi][j] + a2 * ml_part[wv][r][1];
        int qr = q0_hi + r;
#pragma unroll
        for (int db = 0; db < 4; ++db) {
          float val = (a1 * acc_o[mi][db][j] + a2 * O_part[wv][r][db * 16 + lr]) / l;
          Ctx[(size_t)(b * SS + qr) * D_MODEL + h * DH + db * 16 + lr] = __float2bfloat16(val);
        }
      }
  }
}

// ---------------------------------------------------------------------------
extern "C" void kernel_launch(void* const* d_in, const int* in_sizes, int n_in,
                              void* d_out, int out_size, void* d_ws, size_t ws_size,
                              hipStream_t stream) {
  const float* q  = (const float*)d_in[0];
  const float* k  = (const float*)d_in[1];
  const float* v  = (const float*)d_in[2];
  // d_in[3] = additive causal mask — applied analytically in attn_kernel
  const float* bq = (const float*)d_in[5];
  const float* bk = (const float*)d_in[7];
  const float* bv = (const float*)d_in[9];
  const float* bo = (const float*)d_in[11];
  const float* Wq = (const float*)d_in[4];
  const float* Wk = (const float*)d_in[6];
  const float* Wv = (const float*)d_in[8];
  const float* Wo = (const float*)d_in[10];
  float* out = (float*)d_out;

  char* w = (char*)d_ws;
  bf16_t* Aqkv  = (bf16_t*)(w);                       // 3 x [4096][1024] bf16
  bf16_t* WtAll = (bf16_t*)(w + 25165824);            // 4 x [1024][1024] bf16
  bf16_t* Qg    = (bf16_t*)(w + 33554432);            // [4096][1024] bf16
  bf16_t* Kg    = (bf16_t*)(w + 41943040);            // [4096][1024] bf16
  bf16_t* Vt    = (bf16_t*)(w + 50331648);            // [2048][2048] bf16 (per-b, n-major)
  bf16_t* Ctx   = (bf16_t*)(w + 58720256);            // [4096][1024] bf16

  cvt_qkv_kernel<<<2048, 256, 0, stream>>>(q, k, v, Aqkv);
  transpose_w_kernel<<<dim3(32, 32, 4), dim3(32, 8), 0, stream>>>(Wq, Wk, Wv, Wo, WtAll);
  proj_gemm_kernel<<<dim3(8, 32, 3), 256, 0, stream>>>(
      Aqkv, Aqkv + (size_t)MTOT * D_MODEL, Aqkv + 2 * (size_t)MTOT * D_MODEL,
      WtAll, bq, bk, bv, Qg, Kg, Vt);
  attn_kernel<<<dim3(32, 16), 256, 0, stream>>>(Qg, Kg, Vt, Ctx);
  out_gemm_kernel<<<dim3(8, 32), 256, 0, stream>>>(
      Ctx, WtAll + 3 * (size_t)D_MODEL * D_MODEL, bo, out);
}

// Round 8
// 286.219 us; speedup vs baseline: 1.0449x; 1.0309x over previous
//
#include <hip/hip_runtime.h>
#include <hip/hip_bf16.h>
#include <stdint.h>

typedef __bf16 bf16x8 __attribute__((ext_vector_type(8)));
typedef float  f32x4  __attribute__((ext_vector_type(4)));
typedef __hip_bfloat16 bf16_t;

#define D_MODEL 1024
#define NH 16
#define DH 64
#define BB 2
#define SS 2048
#define MTOT (BB*SS)   /* 4096 */
#define NQT (SS/64)    /* 32 q-tiles per (b,h) */

#define GBM 128
#define GBN 128
#define GBK 64

// ---------------------------------------------------------------------------
// fp32 -> bf16 convert for q,k,v (one launch, 3 tensors)
// ---------------------------------------------------------------------------
__global__ void cvt_qkv_kernel(const float* __restrict__ q, const float* __restrict__ k,
                               const float* __restrict__ v, bf16_t* __restrict__ dst) {
  const int n1v = MTOT * D_MODEL / 4;  // float4 count per tensor
  int tid = blockIdx.x * blockDim.x + threadIdx.x;
  int stride = gridDim.x * blockDim.x;
  for (int i = tid; i < 3 * n1v; i += stride) {
    int which = i / n1v;
    int j = i - which * n1v;
    const float4* src = (const float4*)(which == 0 ? q : (which == 1 ? k : v));
    float4 f = src[j];
    union { bf16_t h[4]; short4 s4; } u;
    u.h[0] = __float2bfloat16(f.x);
    u.h[1] = __float2bfloat16(f.y);
    u.h[2] = __float2bfloat16(f.z);
    u.h[3] = __float2bfloat16(f.w);
    ((short4*)dst)[(size_t)which * n1v + j] = u.s4;
  }
}

// ---------------------------------------------------------------------------
// W [K][N] fp32  ->  Wt [N][K] bf16   (z = 0..3 selects Wq,Wk,Wv,Wo)
// ---------------------------------------------------------------------------
__global__ void transpose_w_kernel(const float* __restrict__ W0, const float* __restrict__ W1,
                                   const float* __restrict__ W2, const float* __restrict__ W3,
                                   bf16_t* __restrict__ WtAll) {
  __shared__ float tile[32][33];
  const int z = blockIdx.z;
  const float* W = (z == 0) ? W0 : (z == 1) ? W1 : (z == 2) ? W2 : W3;
  bf16_t* Wt = WtAll + (size_t)z * D_MODEL * D_MODEL;
  const int tx = threadIdx.x, ty = threadIdx.y;
  const int bx = blockIdx.x, by = blockIdx.y;
#pragma unroll
  for (int i = 0; i < 4; ++i)
    tile[ty + i * 8][tx] = W[(size_t)(by * 32 + ty + i * 8) * D_MODEL + bx * 32 + tx];
  __syncthreads();
#pragma unroll
  for (int i = 0; i < 4; ++i)
    Wt[(size_t)(bx * 32 + ty + i * 8) * D_MODEL + by * 32 + tx] =
        __float2bfloat16(tile[tx][ty + i * 8]);
}

// ---------------------------------------------------------------------------
// GEMM mainloop: C[128x128] tile, A [M][K] bf16 row-major, Bt [N][K] bf16.
// ---------------------------------------------------------------------------
__device__ __forceinline__ void g2lds16(const bf16_t* g, bf16_t* l) {
  __builtin_amdgcn_global_load_lds((__attribute__((address_space(1))) void*)(g),
                                   (__attribute__((address_space(3))) void*)(l), 16, 0, 0);
}

__device__ __forceinline__ void gemm_tile_mainloop(const bf16_t* __restrict__ A,
                                                   const bf16_t* __restrict__ Bt,
                                                   bf16_t* As, bf16_t* Bs,
                                                   int m0, int n0, f32x4 acc[4][4]) {
  const int tid = threadIdx.x;
  const int wv = tid >> 6, ln = tid & 63;
  const int wr = wv >> 1, wc = wv & 1;
  const int lr = ln & 15, lg = ln >> 4;

#pragma unroll
  for (int mi = 0; mi < 4; ++mi)
#pragma unroll
    for (int ni = 0; ni < 4; ++ni)
      acc[mi][ni] = (f32x4){0.f, 0.f, 0.f, 0.f};

  for (int kt = 0; kt < D_MODEL / GBK; ++kt) {
#pragma unroll
    for (int c = 0; c < 4; ++c) {
      int chunk = wv * 4 + c;
      int row = chunk * 8 + (ln >> 3);
      int col = (ln & 7) * 8;
      g2lds16(A  + (size_t)(m0 + row) * D_MODEL + kt * GBK + col, As + chunk * 8 * GBK);
      g2lds16(Bt + (size_t)(n0 + row) * D_MODEL + kt * GBK + col, Bs + chunk * 8 * GBK);
    }
    __syncthreads();
#pragma unroll
    for (int ks = 0; ks < 2; ++ks) {
      bf16x8 af[4], bfr[4];
#pragma unroll
      for (int mi = 0; mi < 4; ++mi)
        af[mi] = *(const bf16x8*)(As + (size_t)(wr * 64 + mi * 16 + lr) * GBK + ks * 32 + lg * 8);
#pragma unroll
      for (int ni = 0; ni < 4; ++ni)
        bfr[ni] = *(const bf16x8*)(Bs + (size_t)(wc * 64 + ni * 16 + lr) * GBK + ks * 32 + lg * 8);
#pragma unroll
      for (int mi = 0; mi < 4; ++mi)
#pragma unroll
        for (int ni = 0; ni < 4; ++ni)
          acc[mi][ni] = __builtin_amdgcn_mfma_f32_16x16x32_bf16(af[mi], bfr[ni], acc[mi][ni], 0, 0, 0);
    }
    __syncthreads();
  }
}

// ---------------------------------------------------------------------------
// Projection GEMM: z=0 -> Q, z=1 -> K, z=2 -> V transposed Vt[(b*1024+n)][s]
// ---------------------------------------------------------------------------
__global__ __launch_bounds__(256)
void proj_gemm_kernel(const bf16_t* __restrict__ Aq, const bf16_t* __restrict__ Ak,
                      const bf16_t* __restrict__ Av, const bf16_t* __restrict__ WtAll,
                      const float* __restrict__ bq, const float* __restrict__ bk,
                      const float* __restrict__ bv,
                      bf16_t* __restrict__ Qg, bf16_t* __restrict__ Kg,
                      bf16_t* __restrict__ Vt) {
  __shared__ bf16_t As[GBM * GBK];
  __shared__ bf16_t Bs[GBN * GBK];
  const int z = blockIdx.z;
  const bf16_t* A = (z == 0) ? Aq : (z == 1) ? Ak : Av;
  const bf16_t* Bt = WtAll + (size_t)z * D_MODEL * D_MODEL;
  const float* bias = (z == 0) ? bq : (z == 1) ? bk : bv;
  const int m0 = blockIdx.y * GBM, n0 = blockIdx.x * GBN;

  f32x4 acc[4][4];
  gemm_tile_mainloop(A, Bt, As, Bs, m0, n0, acc);

  const int tid = threadIdx.x;
  const int wv = tid >> 6, ln = tid & 63;
  const int wr = wv >> 1, wc = wv & 1;
  const int lr = ln & 15, lg = ln >> 4;

#pragma unroll
  for (int mi = 0; mi < 4; ++mi) {
#pragma unroll
    for (int ni = 0; ni < 4; ++ni) {
      int ncol = n0 + wc * 64 + ni * 16 + lr;
      float bsv = bias[ncol];
#pragma unroll
      for (int j = 0; j < 4; ++j) {
        int mrow = m0 + wr * 64 + mi * 16 + lg * 4 + j;
        bf16_t hv = __float2bfloat16(acc[mi][ni][j] + bsv);
        if (z == 0) {
          Qg[(size_t)mrow * D_MODEL + ncol] = hv;
        } else if (z == 1) {
          Kg[(size_t)mrow * D_MODEL + ncol] = hv;
        } else {
          int b = mrow >> 11, s = mrow & (SS - 1);
          Vt[(size_t)((b << 10) | ncol) * SS + s] = hv;
        }
      }
    }
  }
}

// ---------------------------------------------------------------------------
// Output GEMM: ctx[M][K] bf16 @ Wo^T [N][K] bf16 + bo -> fp32 out [M][N]
// ---------------------------------------------------------------------------
__global__ __launch_bounds__(256)
void out_gemm_kernel(const bf16_t* __restrict__ Ctx, const bf16_t* __restrict__ Wto,
                     const float* __restrict__ bo, float* __restrict__ out) {
  __shared__ bf16_t As[GBM * GBK];
  __shared__ bf16_t Bs[GBN * GBK];
  const int m0 = blockIdx.y * GBM, n0 = blockIdx.x * GBN;

  f32x4 acc[4][4];
  gemm_tile_mainloop(Ctx, Wto, As, Bs, m0, n0, acc);

  const int tid = threadIdx.x;
  const int wv = tid >> 6, ln = tid & 63;
  const int wr = wv >> 1, wc = wv & 1;
  const int lr = ln & 15, lg = ln >> 4;

#pragma unroll
  for (int mi = 0; mi < 4; ++mi) {
#pragma unroll
    for (int ni = 0; ni < 4; ++ni) {
      int ncol = n0 + wc * 64 + ni * 16 + lr;
      float bsv = bo[ncol];
#pragma unroll
      for (int j = 0; j < 4; ++j) {
        int mrow = m0 + wr * 64 + mi * 16 + lg * 4 + j;
        out[(size_t)mrow * D_MODEL + ncol] = acc[mi][ni][j] + bsv;
      }
    }
  }
}

// ---------------------------------------------------------------------------
// Flash attention, causal — SWAPPED-QK^T structure (R8).
// sc = mfma(K,Q) -> C[kv][q], q = lane&15 -> lane-local softmax:
// row-max = 15 reg fmax + 2 shuffles (was 32 shuffles/tile). m,l,scl are
// per-lane scalars. PV as O^T = mfma(V^T, P^T); P^T built via packed-dword
// LDS bounce (16 dw-writes + 4 b128 reads, stride 44 dwords = conflict-tuned).
// Outer structure from R7: pair (pp, 31-pp), 4 waves, split-KV + LDS merge.
// ---------------------------------------------------------------------------
__device__ __forceinline__ uint32_t pack2bf(float a, float b) {
  union { __hip_bfloat16 h; unsigned short u; } ua, ub;
  ua.h = __float2bfloat16(a);
  ub.h = __float2bfloat16(b);
  return (uint32_t)ua.u | ((uint32_t)ub.u << 16);
}

#define PSTRIDE 44  /* dwords per P row: conflict-tuned, 16B-multiple (176B) */

__device__ __forceinline__ void attn_run(
    f32x4 acc_o[2][4], f32x4 acc_l[2], float m_run[2],
    const bf16x8 qf[2][2], const bf16_t* Kbase, const bf16_t* Vbase,
    uint32_t (*P32)[PSTRIDE], int q0, int t0, int t1, int lr, int lg, bf16x8 onesf) {
  // prologue: K fragments for first tile
  bf16x8 kf_cur[2][4];
#pragma unroll
  for (int ks = 0; ks < 2; ++ks)
#pragma unroll
    for (int kb = 0; kb < 4; ++kb)
      kf_cur[ks][kb] = *(const bf16x8*)(Kbase + (size_t)(t0 * 64 + kb * 16 + lr) * D_MODEL + ks * 32 + lg * 8);

  for (int t = t0; t < t1; ++t) {
    const int kv0 = t * 64;
    f32x4 sc[2][4];
#pragma unroll
    for (int qi = 0; qi < 2; ++qi)
#pragma unroll
      for (int kb = 0; kb < 4; ++kb) sc[qi][kb] = (f32x4){0.f, 0.f, 0.f, 0.f};

    // S^T = K Q^T : C[kv][q], q-col = lane&15
    __builtin_amdgcn_s_setprio(1);
#pragma unroll
    for (int ks = 0; ks < 2; ++ks) {
#pragma unroll
      for (int kb = 0; kb < 4; ++kb) {
        sc[0][kb] = __builtin_amdgcn_mfma_f32_16x16x32_bf16(kf_cur[ks][kb], qf[0][ks], sc[0][kb], 0, 0, 0);
        sc[1][kb] = __builtin_amdgcn_mfma_f32_16x16x32_bf16(kf_cur[ks][kb], qf[1][ks], sc[1][kb], 0, 0, 0);
      }
    }
    __builtin_amdgcn_s_setprio(0);

    // prefetch K(t+1)
    bf16x8 kf_nxt[2][4];
    if (t + 1 < t1) {
#pragma unroll
      for (int ks = 0; ks < 2; ++ks)
#pragma unroll
        for (int kb = 0; kb < 4; ++kb)
          kf_nxt[ks][kb] = *(const bf16x8*)(Kbase + (size_t)(kv0 + 64 + kb * 16 + lr) * D_MODEL + ks * 32 + lg * 8);
    }
    // prefetch V(t): V^T fragment, row d = db*16+lr, k = kv
    bf16x8 vf[2][4];
#pragma unroll
    for (int ks = 0; ks < 2; ++ks)
#pragma unroll
      for (int db = 0; db < 4; ++db)
        vf[ks][db] = *(const bf16x8*)(Vbase + (size_t)(db * 16 + lr) * SS + kv0 + ks * 32 + lg * 8);

    // causal mask: kc = kv0+16kb+4lg+r, qc = q0+qi*16+lr
    if (kv0 + 63 > q0) {
#pragma unroll
      for (int qi = 0; qi < 2; ++qi) {
        int qc = q0 + qi * 16 + lr;
#pragma unroll
        for (int kb = 0; kb < 4; ++kb)
#pragma unroll
          for (int r = 0; r < 4; ++r) {
            int kc = kv0 + kb * 16 + 4 * lg + r;
            if (kc > qc) sc[qi][kb][r] = -1e30f;
          }
      }
    }

    // lane-local softmax per q-column
#pragma unroll
    for (int qi = 0; qi < 2; ++qi) {
      float vm = sc[qi][0][0];
#pragma unroll
      for (int kb = 0; kb < 4; ++kb)
#pragma unroll
        for (int r = 0; r < 4; ++r) vm = fmaxf(vm, sc[qi][kb][r]);
      vm = fmaxf(vm, __shfl_xor(vm, 16, 64));
      vm = fmaxf(vm, __shfl_xor(vm, 32, 64));
      float mo = m_run[qi];
      float mn = fmaxf(mo, vm);
      float scl = __expf(mo - mn);
      m_run[qi] = mn;
#pragma unroll
      for (int kb = 0; kb < 4; ++kb)
#pragma unroll
        for (int hh = 0; hh < 2; ++hh) {
          float p0 = __expf(sc[qi][kb][2 * hh]     - mn);
          float p1 = __expf(sc[qi][kb][2 * hh + 1] - mn);
          P32[qi * 16 + lr][8 * kb + 2 * lg + hh] = pack2bf(p0, p1);
        }
#pragma unroll
      for (int r = 0; r < 4; ++r) acc_l[qi][r] *= scl;
#pragma unroll
      for (int db = 0; db < 4; ++db)
#pragma unroll
        for (int r = 0; r < 4; ++r) acc_o[qi][db][r] *= scl;
    }

    // wave-internal LDS turnaround (rule #18 discipline)
    asm volatile("s_waitcnt lgkmcnt(0)" ::: "memory");
    __builtin_amdgcn_sched_barrier(0);

    // P^T fragments: B-operand needs [k=kv=32ks+8lg+j][col=q=lane&15]
    bf16x8 pb[2][2];
#pragma unroll
    for (int qi = 0; qi < 2; ++qi)
#pragma unroll
      for (int ks = 0; ks < 2; ++ks)
        pb[qi][ks] = *(const bf16x8*)&P32[qi * 16 + lr][16 * ks + 4 * lg];

    // O^T += V^T P^T ; l += ones * P^T
    __builtin_amdgcn_s_setprio(1);
#pragma unroll
    for (int ks = 0; ks < 2; ++ks) {
#pragma unroll
      for (int qi = 0; qi < 2; ++qi) {
        acc_l[qi] = __builtin_amdgcn_mfma_f32_16x16x32_bf16(onesf, pb[qi][ks], acc_l[qi], 0, 0, 0);
#pragma unroll
        for (int db = 0; db < 4; ++db)
          acc_o[qi][db] = __builtin_amdgcn_mfma_f32_16x16x32_bf16(vf[ks][db], pb[qi][ks], acc_o[qi][db], 0, 0, 0);
      }
    }
    __builtin_amdgcn_s_setprio(0);

    if (t + 1 < t1) {
#pragma unroll
      for (int ks = 0; ks < 2; ++ks)
#pragma unroll
        for (int kb = 0; kb < 4; ++kb)
          kf_cur[ks][kb] = kf_nxt[ks][kb];
    }
  }
}

__device__ __forceinline__ void attn_load_q(bf16x8 qf[2][2], const bf16_t* Qbase,
                                            int q0, int lr, int lg) {
#pragma unroll
  for (int qi = 0; qi < 2; ++qi)
#pragma unroll
    for (int ks = 0; ks < 2; ++ks) {
      bf16x8 raw = *(const bf16x8*)(Qbase + (size_t)(q0 + qi * 16 + lr) * D_MODEL + ks * 32 + lg * 8);
#pragma unroll
      for (int j = 0; j < 8; ++j) raw[j] = (__bf16)((float)raw[j] * 0.125f);
      qf[qi][ks] = raw;
    }
}

__device__ __forceinline__ void attn_init(f32x4 acc_o[2][4], f32x4 acc_l[2], float m_run[2]) {
#pragma unroll
  for (int qi = 0; qi < 2; ++qi) {
#pragma unroll
    for (int db = 0; db < 4; ++db) acc_o[qi][db] = (f32x4){0.f, 0.f, 0.f, 0.f};
    acc_l[qi] = (f32x4){0.f, 0.f, 0.f, 0.f};
    m_run[qi] = -1e30f;
  }
}

// O^T regs -> bf16 LDS bounce -> coalesced row-major store (64B segments)
__device__ __forceinline__ void store_ctx_tile(
    uint32_t (*P32)[PSTRIDE], const f32x4 acc_o[2][4], const f32x4 acc_l[2],
    bf16_t* __restrict__ Ctx, int b, int h, int q0, int ln, int lr, int lg) {
#pragma unroll
  for (int qi = 0; qi < 2; ++qi) {
    float rl = 1.0f / acc_l[qi][0];
#pragma unroll
    for (int db = 0; db < 4; ++db)
#pragma unroll
      for (int hh = 0; hh < 2; ++hh)
        P32[qi * 16 + lr][8 * db + 2 * lg + hh] =
            pack2bf(acc_o[qi][db][2 * hh] * rl, acc_o[qi][db][2 * hh + 1] * rl);
  }
  asm volatile("s_waitcnt lgkmcnt(0)" ::: "memory");
  __builtin_amdgcn_sched_barrier(0);
#pragma unroll
  for (int c = 0; c < 4; ++c) {
    int row = (ln >> 2) + 16 * (c >> 1);
    int dwc = (ln & 3) * 4 + 16 * (c & 1);
    bf16x8 v = *(const bf16x8*)&P32[row][dwc];
    *(bf16x8*)(Ctx + (size_t)(b * SS + q0 + row) * D_MODEL + h * DH + dwc * 2) = v;
  }
}

__global__ __launch_bounds__(256)
void attn_kernel(const bf16_t* __restrict__ Qg, const bf16_t* __restrict__ Kg,
                 const bf16_t* __restrict__ Vt, bf16_t* __restrict__ Ctx) {
  __shared__ __align__(16) uint32_t P32[4][32][PSTRIDE];
  __shared__ __align__(16) float O_part[2][32][68];   // partial O^T, [q][d]+pad
  __shared__ float ml_part[2][32][2];                 // [q][0]=m, [1]=l
  const int bh = blockIdx.x;
  const int pp = blockIdx.y;
  const int b = bh >> 4, h = bh & 15;
  const int wv = threadIdx.x >> 6, ln = threadIdx.x & 63;
  const int lr = ln & 15, lg = ln >> 4;

  const int qt_lo = pp, qt_hi = NQT - 1 - pp;
  const int h0 = 16 - pp;                 // high tile KV split point
  const int rh = wv & 1;                  // row half within the 64-row tile

  const size_t qkbase = (size_t)b * SS * D_MODEL + (size_t)h * DH;
  const bf16_t* Qbase = Qg + qkbase;
  const bf16_t* Kbase = Kg + qkbase;
  const bf16_t* Vbase = Vt + (size_t)(bh * 64) * SS;

  bf16x8 onesf;
#pragma unroll
  for (int j = 0; j < 8; ++j) onesf[j] = (__bf16)1.0f;

  bf16x8 qf[2][2];
  f32x4 acc_o[2][4];
  f32x4 acc_l[2];
  float m_run[2];
  const int q0_hi = qt_hi * 64 + rh * 32;

  if (wv < 2) {
    // ---- low tile, full KV range [0, pp+1), direct store ----
    const int q0_lo = qt_lo * 64 + rh * 32;
    attn_load_q(qf, Qbase, q0_lo, lr, lg);
    attn_init(acc_o, acc_l, m_run);
    attn_run(acc_o, acc_l, m_run, qf, Kbase, Vbase, P32[wv], q0_lo, 0, pp + 1, lr, lg, onesf);
    store_ctx_tile(P32[wv], acc_o, acc_l, Ctx, b, h, q0_lo, ln, lr, lg);

    // ---- high tile part A: KV [0, h0), keep in regs for merge ----
    attn_load_q(qf, Qbase, q0_hi, lr, lg);
    attn_init(acc_o, acc_l, m_run);
    attn_run(acc_o, acc_l, m_run, qf, Kbase, Vbase, P32[wv], q0_hi, 0, h0, lr, lg, onesf);
  } else {
    // ---- high tile part B: KV [h0, 32-pp) incl. diagonal ----
    attn_load_q(qf, Qbase, q0_hi, lr, lg);
    attn_init(acc_o, acc_l, m_run);
    attn_run(acc_o, acc_l, m_run, qf, Kbase, Vbase, P32[wv], q0_hi, h0, NQT - pp, lr, lg, onesf);
    // dump partial (O^T, m, l) to LDS
    const int pidx = wv - 2;
#pragma unroll
    for (int qi = 0; qi < 2; ++qi) {
#pragma unroll
      for (int db = 0; db < 4; ++db)
        *(f32x4*)&O_part[pidx][qi * 16 + lr][16 * db + 4 * lg] = acc_o[qi][db];
      if (lg == 0) {
        ml_part[pidx][qi * 16 + lr][0] = m_run[qi];
        ml_part[pidx][qi * 16 + lr][1] = acc_l[qi][0];
      }
    }
  }

  __syncthreads();

  if (wv < 2) {
    // ---- merge part A (regs) with part B (LDS), store high tile ----
#pragma unroll
    for (int qi = 0; qi < 2; ++qi) {
      float m1 = m_run[qi];
      float m2 = ml_part[wv][qi * 16 + lr][0];
      float mn = fmaxf(m1, m2);
      float a1 = __expf(m1 - mn);
      float a2 = __expf(m2 - mn);
      float l = a1 * acc_l[qi][0] + a2 * ml_part[wv][qi * 16 + lr][1];
#pragma unroll
      for (int db = 0; db < 4; ++db) {
        f32x4 po = *(const f32x4*)&O_part[wv][qi * 16 + lr][16 * db + 4 * lg];
#pragma unroll
        for (int r = 0; r < 4; ++r)
          acc_o[qi][db][r] = a1 * acc_o[qi][db][r] + a2 * po[r];
      }
      acc_l[qi] = (f32x4){l, l, l, l};
    }
    store_ctx_tile(P32[wv], acc_o, acc_l, Ctx, b, h, q0_hi, ln, lr, lg);
  }
}

// ---------------------------------------------------------------------------
extern "C" void kernel_launch(void* const* d_in, const int* in_sizes, int n_in,
                              void* d_out, int out_size, void* d_ws, size_t ws_size,
                              hipStream_t stream) {
  const float* q  = (const float*)d_in[0];
  const float* k  = (const float*)d_in[1];
  const float* v  = (const float*)d_in[2];
  // d_in[3] = additive causal mask — applied analytically in attn_kernel
  const float* bq = (const float*)d_in[5];
  const float* bk = (const float*)d_in[7];
  const float* bv = (const float*)d_in[9];
  const float* bo = (const float*)d_in[11];
  const float* Wq = (const float*)d_in[4];
  const float* Wk = (const float*)d_in[6];
  const float* Wv = (const float*)d_in[8];
  const float* Wo = (const float*)d_in[10];
  float* out = (float*)d_out;

  char* w = (char*)d_ws;
  bf16_t* Aqkv  = (bf16_t*)(w);                       // 3 x [4096][1024] bf16
  bf16_t* WtAll = (bf16_t*)(w + 25165824);            // 4 x [1024][1024] bf16
  bf16_t* Qg    = (bf16_t*)(w + 33554432);            // [4096][1024] bf16
  bf16_t* Kg    = (bf16_t*)(w + 41943040);            // [4096][1024] bf16
  bf16_t* Vt    = (bf16_t*)(w + 50331648);            // [2048][2048] bf16 (per-b, n-major)
  bf16_t* Ctx   = (bf16_t*)(w + 58720256);            // [4096][1024] bf16

  cvt_qkv_kernel<<<2048, 256, 0, stream>>>(q, k, v, Aqkv);
  transpose_w_kernel<<<dim3(32, 32, 4), dim3(32, 8), 0, stream>>>(Wq, Wk, Wv, Wo, WtAll);
  proj_gemm_kernel<<<dim3(8, 32, 3), 256, 0, stream>>>(
      Aqkv, Aqkv + (size_t)MTOT * D_MODEL, Aqkv + 2 * (size_t)MTOT * D_MODEL,
      WtAll, bq, bk, bv, Qg, Kg, Vt);
  attn_kernel<<<dim3(32, 16), 256, 0, stream>>>(Qg, Kg, Vt, Ctx);
  out_gemm_kernel<<<dim3(8, 32), 256, 0, stream>>>(
      Ctx, WtAll + 3 * (size_t)D_MODEL * D_MODEL, bo, out);
}

// Round 9
// 275.637 us; speedup vs baseline: 1.0850x; 1.0384x over previous
//
#include <hip/hip_runtime.h>
#include <hip/hip_bf16.h>
#include <stdint.h>

typedef __bf16 bf16x8 __attribute__((ext_vector_type(8)));
typedef float  f32x4  __attribute__((ext_vector_type(4)));
typedef __hip_bfloat16 bf16_t;

#define D_MODEL 1024
#define NH 16
#define DH 64
#define BB 2
#define SS 2048
#define MTOT (BB*SS)   /* 4096 */
#define NQT (SS/64)    /* 32 q-tiles per (b,h) */

#define GBM 128
#define GBN 64
#define GBK 64

// ---------------------------------------------------------------------------
// fp32 -> bf16 convert for q,k,v (one launch, 3 tensors)
// ---------------------------------------------------------------------------
__global__ void cvt_qkv_kernel(const float* __restrict__ q, const float* __restrict__ k,
                               const float* __restrict__ v, bf16_t* __restrict__ dst) {
  const int n1v = MTOT * D_MODEL / 4;  // float4 count per tensor
  int tid = blockIdx.x * blockDim.x + threadIdx.x;
  int stride = gridDim.x * blockDim.x;
  for (int i = tid; i < 3 * n1v; i += stride) {
    int which = i / n1v;
    int j = i - which * n1v;
    const float4* src = (const float4*)(which == 0 ? q : (which == 1 ? k : v));
    float4 f = src[j];
    union { bf16_t h[4]; short4 s4; } u;
    u.h[0] = __float2bfloat16(f.x);
    u.h[1] = __float2bfloat16(f.y);
    u.h[2] = __float2bfloat16(f.z);
    u.h[3] = __float2bfloat16(f.w);
    ((short4*)dst)[(size_t)which * n1v + j] = u.s4;
  }
}

// ---------------------------------------------------------------------------
// W [K][N] fp32  ->  Wt [N][K] bf16   (z = 0..3 selects Wq,Wk,Wv,Wo)
// ---------------------------------------------------------------------------
__global__ void transpose_w_kernel(const float* __restrict__ W0, const float* __restrict__ W1,
                                   const float* __restrict__ W2, const float* __restrict__ W3,
                                   bf16_t* __restrict__ WtAll) {
  __shared__ float tile[32][33];
  const int z = blockIdx.z;
  const float* W = (z == 0) ? W0 : (z == 1) ? W1 : (z == 2) ? W2 : W3;
  bf16_t* Wt = WtAll + (size_t)z * D_MODEL * D_MODEL;
  const int tx = threadIdx.x, ty = threadIdx.y;
  const int bx = blockIdx.x, by = blockIdx.y;
#pragma unroll
  for (int i = 0; i < 4; ++i)
    tile[ty + i * 8][tx] = W[(size_t)(by * 32 + ty + i * 8) * D_MODEL + bx * 32 + tx];
  __syncthreads();
#pragma unroll
  for (int i = 0; i < 4; ++i)
    Wt[(size_t)(bx * 32 + ty + i * 8) * D_MODEL + by * 32 + tx] =
        __float2bfloat16(tile[tx][ty + i * 8]);
}

// ---------------------------------------------------------------------------
// GEMM mainloop: C[128x64] tile (BN=64 for occupancy: latency-bound regime,
// R9 change — 2x resident blocks/CU vs BN=128). 4 waves 2x2 over (2x64 M,
// 2x32 N), each wave 64x32 = 4x2 frags. global_load_lds width-16 staging.
// ---------------------------------------------------------------------------
__device__ __forceinline__ void g2lds16(const bf16_t* g, bf16_t* l) {
  __builtin_amdgcn_global_load_lds((__attribute__((address_space(1))) void*)(g),
                                   (__attribute__((address_space(3))) void*)(l), 16, 0, 0);
}

__device__ __forceinline__ void gemm_tile_mainloop(const bf16_t* __restrict__ A,
                                                   const bf16_t* __restrict__ Bt,
                                                   bf16_t* As, bf16_t* Bs,
                                                   int m0, int n0, f32x4 acc[4][2]) {
  const int tid = threadIdx.x;
  const int wv = tid >> 6, ln = tid & 63;
  const int wr = wv >> 1, wc = wv & 1;
  const int lr = ln & 15, lg = ln >> 4;

#pragma unroll
  for (int mi = 0; mi < 4; ++mi)
#pragma unroll
    for (int ni = 0; ni < 2; ++ni)
      acc[mi][ni] = (f32x4){0.f, 0.f, 0.f, 0.f};

  for (int kt = 0; kt < D_MODEL / GBK; ++kt) {
    // stage A (128x64 = 16 chunks) and B (64x64 = 8 chunks); 6 chunks/wave
#pragma unroll
    for (int c = 0; c < 6; ++c) {
      int chunk = wv * 6 + c;
      int row8 = ln >> 3;
      int col = (ln & 7) * 8;
      if (chunk < 16) {
        g2lds16(A  + (size_t)(m0 + chunk * 8 + row8) * D_MODEL + kt * GBK + col,
                As + chunk * 8 * GBK);
      } else {
        g2lds16(Bt + (size_t)(n0 + (chunk - 16) * 8 + row8) * D_MODEL + kt * GBK + col,
                Bs + (chunk - 16) * 8 * GBK);
      }
    }
    __syncthreads();
#pragma unroll
    for (int ks = 0; ks < 2; ++ks) {
      bf16x8 af[4], bfr[2];
#pragma unroll
      for (int mi = 0; mi < 4; ++mi)
        af[mi] = *(const bf16x8*)(As + (size_t)(wr * 64 + mi * 16 + lr) * GBK + ks * 32 + lg * 8);
#pragma unroll
      for (int ni = 0; ni < 2; ++ni)
        bfr[ni] = *(const bf16x8*)(Bs + (size_t)(wc * 32 + ni * 16 + lr) * GBK + ks * 32 + lg * 8);
#pragma unroll
      for (int mi = 0; mi < 4; ++mi)
#pragma unroll
        for (int ni = 0; ni < 2; ++ni)
          acc[mi][ni] = __builtin_amdgcn_mfma_f32_16x16x32_bf16(af[mi], bfr[ni], acc[mi][ni], 0, 0, 0);
    }
    __syncthreads();
  }
}

// ---------------------------------------------------------------------------
// Projection GEMM: z=0 -> Q, z=1 -> K, z=2 -> V transposed Vt[(b*1024+n)][s]
// ---------------------------------------------------------------------------
__global__ __launch_bounds__(256)
void proj_gemm_kernel(const bf16_t* __restrict__ Aq, const bf16_t* __restrict__ Ak,
                      const bf16_t* __restrict__ Av, const bf16_t* __restrict__ WtAll,
                      const float* __restrict__ bq, const float* __restrict__ bk,
                      const float* __restrict__ bv,
                      bf16_t* __restrict__ Qg, bf16_t* __restrict__ Kg,
                      bf16_t* __restrict__ Vt) {
  __shared__ bf16_t As[GBM * GBK];
  __shared__ bf16_t Bs[GBN * GBK];
  const int z = blockIdx.z;
  const bf16_t* A = (z == 0) ? Aq : (z == 1) ? Ak : Av;
  const bf16_t* Bt = WtAll + (size_t)z * D_MODEL * D_MODEL;
  const float* bias = (z == 0) ? bq : (z == 1) ? bk : bv;
  const int m0 = blockIdx.y * GBM, n0 = blockIdx.x * GBN;

  f32x4 acc[4][2];
  gemm_tile_mainloop(A, Bt, As, Bs, m0, n0, acc);

  const int tid = threadIdx.x;
  const int wv = tid >> 6, ln = tid & 63;
  const int wr = wv >> 1, wc = wv & 1;
  const int lr = ln & 15, lg = ln >> 4;

#pragma unroll
  for (int mi = 0; mi < 4; ++mi) {
#pragma unroll
    for (int ni = 0; ni < 2; ++ni) {
      int ncol = n0 + wc * 32 + ni * 16 + lr;
      float bsv = bias[ncol];
#pragma unroll
      for (int j = 0; j < 4; ++j) {
        int mrow = m0 + wr * 64 + mi * 16 + lg * 4 + j;
        bf16_t hv = __float2bfloat16(acc[mi][ni][j] + bsv);
        if (z == 0) {
          Qg[(size_t)mrow * D_MODEL + ncol] = hv;
        } else if (z == 1) {
          Kg[(size_t)mrow * D_MODEL + ncol] = hv;
        } else {
          int b = mrow >> 11, s = mrow & (SS - 1);
          Vt[(size_t)((b << 10) | ncol) * SS + s] = hv;
        }
      }
    }
  }
}

// ---------------------------------------------------------------------------
// Output GEMM: ctx[M][K] bf16 @ Wo^T [N][K] bf16 + bo -> fp32 out [M][N]
// ---------------------------------------------------------------------------
__global__ __launch_bounds__(256)
void out_gemm_kernel(const bf16_t* __restrict__ Ctx, const bf16_t* __restrict__ Wto,
                     const float* __restrict__ bo, float* __restrict__ out) {
  __shared__ bf16_t As[GBM * GBK];
  __shared__ bf16_t Bs[GBN * GBK];
  const int m0 = blockIdx.y * GBM, n0 = blockIdx.x * GBN;

  f32x4 acc[4][2];
  gemm_tile_mainloop(Ctx, Wto, As, Bs, m0, n0, acc);

  const int tid = threadIdx.x;
  const int wv = tid >> 6, ln = tid & 63;
  const int wr = wv >> 1, wc = wv & 1;
  const int lr = ln & 15, lg = ln >> 4;

#pragma unroll
  for (int mi = 0; mi < 4; ++mi) {
#pragma unroll
    for (int ni = 0; ni < 2; ++ni) {
      int ncol = n0 + wc * 32 + ni * 16 + lr;
      float bsv = bo[ncol];
#pragma unroll
      for (int j = 0; j < 4; ++j) {
        int mrow = m0 + wr * 64 + mi * 16 + lg * 4 + j;
        out[(size_t)mrow * D_MODEL + ncol] = acc[mi][ni][j] + bsv;
      }
    }
  }
}

// ---------------------------------------------------------------------------
// Flash attention, causal — SWAPPED-QK^T structure (unchanged from R8).
// ---------------------------------------------------------------------------
__device__ __forceinline__ uint32_t pack2bf(float a, float b) {
  union { __hip_bfloat16 h; unsigned short u; } ua, ub;
  ua.h = __float2bfloat16(a);
  ub.h = __float2bfloat16(b);
  return (uint32_t)ua.u | ((uint32_t)ub.u << 16);
}

#define PSTRIDE 44  /* dwords per P row: conflict-tuned, 16B-multiple (176B) */

__device__ __forceinline__ void attn_run(
    f32x4 acc_o[2][4], f32x4 acc_l[2], float m_run[2],
    const bf16x8 qf[2][2], const bf16_t* Kbase, const bf16_t* Vbase,
    uint32_t (*P32)[PSTRIDE], int q0, int t0, int t1, int lr, int lg, bf16x8 onesf) {
  // prologue: K fragments for first tile
  bf16x8 kf_cur[2][4];
#pragma unroll
  for (int ks = 0; ks < 2; ++ks)
#pragma unroll
    for (int kb = 0; kb < 4; ++kb)
      kf_cur[ks][kb] = *(const bf16x8*)(Kbase + (size_t)(t0 * 64 + kb * 16 + lr) * D_MODEL + ks * 32 + lg * 8);

  for (int t = t0; t < t1; ++t) {
    const int kv0 = t * 64;
    f32x4 sc[2][4];
#pragma unroll
    for (int qi = 0; qi < 2; ++qi)
#pragma unroll
      for (int kb = 0; kb < 4; ++kb) sc[qi][kb] = (f32x4){0.f, 0.f, 0.f, 0.f};

    // S^T = K Q^T : C[kv][q], q-col = lane&15
    __builtin_amdgcn_s_setprio(1);
#pragma unroll
    for (int ks = 0; ks < 2; ++ks) {
#pragma unroll
      for (int kb = 0; kb < 4; ++kb) {
        sc[0][kb] = __builtin_amdgcn_mfma_f32_16x16x32_bf16(kf_cur[ks][kb], qf[0][ks], sc[0][kb], 0, 0, 0);
        sc[1][kb] = __builtin_amdgcn_mfma_f32_16x16x32_bf16(kf_cur[ks][kb], qf[1][ks], sc[1][kb], 0, 0, 0);
      }
    }
    __builtin_amdgcn_s_setprio(0);

    // prefetch K(t+1)
    bf16x8 kf_nxt[2][4];
    if (t + 1 < t1) {
#pragma unroll
      for (int ks = 0; ks < 2; ++ks)
#pragma unroll
        for (int kb = 0; kb < 4; ++kb)
          kf_nxt[ks][kb] = *(const bf16x8*)(Kbase + (size_t)(kv0 + 64 + kb * 16 + lr) * D_MODEL + ks * 32 + lg * 8);
    }
    // prefetch V(t): V^T fragment, row d = db*16+lr, k = kv
    bf16x8 vf[2][4];
#pragma unroll
    for (int ks = 0; ks < 2; ++ks)
#pragma unroll
      for (int db = 0; db < 4; ++db)
        vf[ks][db] = *(const bf16x8*)(Vbase + (size_t)(db * 16 + lr) * SS + kv0 + ks * 32 + lg * 8);

    // causal mask: kc = kv0+16kb+4lg+r, qc = q0+qi*16+lr
    if (kv0 + 63 > q0) {
#pragma unroll
      for (int qi = 0; qi < 2; ++qi) {
        int qc = q0 + qi * 16 + lr;
#pragma unroll
        for (int kb = 0; kb < 4; ++kb)
#pragma unroll
          for (int r = 0; r < 4; ++r) {
            int kc = kv0 + kb * 16 + 4 * lg + r;
            if (kc > qc) sc[qi][kb][r] = -1e30f;
          }
      }
    }

    // lane-local softmax per q-column
#pragma unroll
    for (int qi = 0; qi < 2; ++qi) {
      float vm = sc[qi][0][0];
#pragma unroll
      for (int kb = 0; kb < 4; ++kb)
#pragma unroll
        for (int r = 0; r < 4; ++r) vm = fmaxf(vm, sc[qi][kb][r]);
      vm = fmaxf(vm, __shfl_xor(vm, 16, 64));
      vm = fmaxf(vm, __shfl_xor(vm, 32, 64));
      float mo = m_run[qi];
      float mn = fmaxf(mo, vm);
      float scl = __expf(mo - mn);
      m_run[qi] = mn;
#pragma unroll
      for (int kb = 0; kb < 4; ++kb)
#pragma unroll
        for (int hh = 0; hh < 2; ++hh) {
          float p0 = __expf(sc[qi][kb][2 * hh]     - mn);
          float p1 = __expf(sc[qi][kb][2 * hh + 1] - mn);
          P32[qi * 16 + lr][8 * kb + 2 * lg + hh] = pack2bf(p0, p1);
        }
#pragma unroll
      for (int r = 0; r < 4; ++r) acc_l[qi][r] *= scl;
#pragma unroll
      for (int db = 0; db < 4; ++db)
#pragma unroll
        for (int r = 0; r < 4; ++r) acc_o[qi][db][r] *= scl;
    }

    // wave-internal LDS turnaround (rule #18 discipline)
    asm volatile("s_waitcnt lgkmcnt(0)" ::: "memory");
    __builtin_amdgcn_sched_barrier(0);

    // P^T fragments: B-operand needs [k=kv=32ks+8lg+j][col=q=lane&15]
    bf16x8 pb[2][2];
#pragma unroll
    for (int qi = 0; qi < 2; ++qi)
#pragma unroll
      for (int ks = 0; ks < 2; ++ks)
        pb[qi][ks] = *(const bf16x8*)&P32[qi * 16 + lr][16 * ks + 4 * lg];

    // O^T += V^T P^T ; l += ones * P^T
    __builtin_amdgcn_s_setprio(1);
#pragma unroll
    for (int ks = 0; ks < 2; ++ks) {
#pragma unroll
      for (int qi = 0; qi < 2; ++qi) {
        acc_l[qi] = __builtin_amdgcn_mfma_f32_16x16x32_bf16(onesf, pb[qi][ks], acc_l[qi], 0, 0, 0);
#pragma unroll
        for (int db = 0; db < 4; ++db)
          acc_o[qi][db] = __builtin_amdgcn_mfma_f32_16x16x32_bf16(vf[ks][db], pb[qi][ks], acc_o[qi][db], 0, 0, 0);
      }
    }
    __builtin_amdgcn_s_setprio(0);

    if (t + 1 < t1) {
#pragma unroll
      for (int ks = 0; ks < 2; ++ks)
#pragma unroll
        for (int kb = 0; kb < 4; ++kb)
          kf_cur[ks][kb] = kf_nxt[ks][kb];
    }
  }
}

__device__ __forceinline__ void attn_load_q(bf16x8 qf[2][2], const bf16_t* Qbase,
                                            int q0, int lr, int lg) {
#pragma unroll
  for (int qi = 0; qi < 2; ++qi)
#pragma unroll
    for (int ks = 0; ks < 2; ++ks) {
      bf16x8 raw = *(const bf16x8*)(Qbase + (size_t)(q0 + qi * 16 + lr) * D_MODEL + ks * 32 + lg * 8);
#pragma unroll
      for (int j = 0; j < 8; ++j) raw[j] = (__bf16)((float)raw[j] * 0.125f);
      qf[qi][ks] = raw;
    }
}

__device__ __forceinline__ void attn_init(f32x4 acc_o[2][4], f32x4 acc_l[2], float m_run[2]) {
#pragma unroll
  for (int qi = 0; qi < 2; ++qi) {
#pragma unroll
    for (int db = 0; db < 4; ++db) acc_o[qi][db] = (f32x4){0.f, 0.f, 0.f, 0.f};
    acc_l[qi] = (f32x4){0.f, 0.f, 0.f, 0.f};
    m_run[qi] = -1e30f;
  }
}

// O^T regs -> bf16 LDS bounce -> coalesced row-major store (64B segments)
__device__ __forceinline__ void store_ctx_tile(
    uint32_t (*P32)[PSTRIDE], const f32x4 acc_o[2][4], const f32x4 acc_l[2],
    bf16_t* __restrict__ Ctx, int b, int h, int q0, int ln, int lr, int lg) {
#pragma unroll
  for (int qi = 0; qi < 2; ++qi) {
    float rl = 1.0f / acc_l[qi][0];
#pragma unroll
    for (int db = 0; db < 4; ++db)
#pragma unroll
      for (int hh = 0; hh < 2; ++hh)
        P32[qi * 16 + lr][8 * db + 2 * lg + hh] =
            pack2bf(acc_o[qi][db][2 * hh] * rl, acc_o[qi][db][2 * hh + 1] * rl);
  }
  asm volatile("s_waitcnt lgkmcnt(0)" ::: "memory");
  __builtin_amdgcn_sched_barrier(0);
#pragma unroll
  for (int c = 0; c < 4; ++c) {
    int row = (ln >> 2) + 16 * (c >> 1);
    int dwc = (ln & 3) * 4 + 16 * (c & 1);
    bf16x8 v = *(const bf16x8*)&P32[row][dwc];
    *(bf16x8*)(Ctx + (size_t)(b * SS + q0 + row) * D_MODEL + h * DH + dwc * 2) = v;
  }
}

__global__ __launch_bounds__(256)
void attn_kernel(const bf16_t* __restrict__ Qg, const bf16_t* __restrict__ Kg,
                 const bf16_t* __restrict__ Vt, bf16_t* __restrict__ Ctx) {
  __shared__ __align__(16) uint32_t P32[4][32][PSTRIDE];
  __shared__ __align__(16) float O_part[2][32][68];   // partial O^T, [q][d]+pad
  __shared__ float ml_part[2][32][2];                 // [q][0]=m, [1]=l
  const int bh = blockIdx.x;
  const int pp = blockIdx.y;
  const int b = bh >> 4, h = bh & 15;
  const int wv = threadIdx.x >> 6, ln = threadIdx.x & 63;
  const int lr = ln & 15, lg = ln >> 4;

  const int qt_lo = pp, qt_hi = NQT - 1 - pp;
  const int h0 = 16 - pp;                 // high tile KV split point
  const int rh = wv & 1;                  // row half within the 64-row tile

  const size_t qkbase = (size_t)b * SS * D_MODEL + (size_t)h * DH;
  const bf16_t* Qbase = Qg + qkbase;
  const bf16_t* Kbase = Kg + qkbase;
  const bf16_t* Vbase = Vt + (size_t)(bh * 64) * SS;

  bf16x8 onesf;
#pragma unroll
  for (int j = 0; j < 8; ++j) onesf[j] = (__bf16)1.0f;

  bf16x8 qf[2][2];
  f32x4 acc_o[2][4];
  f32x4 acc_l[2];
  float m_run[2];
  const int q0_hi = qt_hi * 64 + rh * 32;

  if (wv < 2) {
    // ---- low tile, full KV range [0, pp+1), direct store ----
    const int q0_lo = qt_lo * 64 + rh * 32;
    attn_load_q(qf, Qbase, q0_lo, lr, lg);
    attn_init(acc_o, acc_l, m_run);
    attn_run(acc_o, acc_l, m_run, qf, Kbase, Vbase, P32[wv], q0_lo, 0, pp + 1, lr, lg, onesf);
    store_ctx_tile(P32[wv], acc_o, acc_l, Ctx, b, h, q0_lo, ln, lr, lg);

    // ---- high tile part A: KV [0, h0), keep in regs for merge ----
    attn_load_q(qf, Qbase, q0_hi, lr, lg);
    attn_init(acc_o, acc_l, m_run);
    attn_run(acc_o, acc_l, m_run, qf, Kbase, Vbase, P32[wv], q0_hi, 0, h0, lr, lg, onesf);
  } else {
    // ---- high tile part B: KV [h0, 32-pp) incl. diagonal ----
    attn_load_q(qf, Qbase, q0_hi, lr, lg);
    attn_init(acc_o, acc_l, m_run);
    attn_run(acc_o, acc_l, m_run, qf, Kbase, Vbase, P32[wv], q0_hi, h0, NQT - pp, lr, lg, onesf);
    // dump partial (O^T, m, l) to LDS
    const int pidx = wv - 2;
#pragma unroll
    for (int qi = 0; qi < 2; ++qi) {
#pragma unroll
      for (int db = 0; db < 4; ++db)
        *(f32x4*)&O_part[pidx][qi * 16 + lr][16 * db + 4 * lg] = acc_o[qi][db];
      if (lg == 0) {
        ml_part[pidx][qi * 16 + lr][0] = m_run[qi];
        ml_part[pidx][qi * 16 + lr][1] = acc_l[qi][0];
      }
    }
  }

  __syncthreads();

  if (wv < 2) {
    // ---- merge part A (regs) with part B (LDS), store high tile ----
#pragma unroll
    for (int qi = 0; qi < 2; ++qi) {
      float m1 = m_run[qi];
      float m2 = ml_part[wv][qi * 16 + lr][0];
      float mn = fmaxf(m1, m2);
      float a1 = __expf(m1 - mn);
      float a2 = __expf(m2 - mn);
      float l = a1 * acc_l[qi][0] + a2 * ml_part[wv][qi * 16 + lr][1];
#pragma unroll
      for (int db = 0; db < 4; ++db) {
        f32x4 po = *(const f32x4*)&O_part[wv][qi * 16 + lr][16 * db + 4 * lg];
#pragma unroll
        for (int r = 0; r < 4; ++r)
          acc_o[qi][db][r] = a1 * acc_o[qi][db][r] + a2 * po[r];
      }
      acc_l[qi] = (f32x4){l, l, l, l};
    }
    store_ctx_tile(P32[wv], acc_o, acc_l, Ctx, b, h, q0_hi, ln, lr, lg);
  }
}

// ---------------------------------------------------------------------------
extern "C" void kernel_launch(void* const* d_in, const int* in_sizes, int n_in,
                              void* d_out, int out_size, void* d_ws, size_t ws_size,
                              hipStream_t stream) {
  const float* q  = (const float*)d_in[0];
  const float* k  = (const float*)d_in[1];
  const float* v  = (const float*)d_in[2];
  // d_in[3] = additive causal mask — applied analytically in attn_kernel
  const float* bq = (const float*)d_in[5];
  const float* bk = (const float*)d_in[7];
  const float* bv = (const float*)d_in[9];
  const float* bo = (const float*)d_in[11];
  const float* Wq = (const float*)d_in[4];
  const float* Wk = (const float*)d_in[6];
  const float* Wv = (const float*)d_in[8];
  const float* Wo = (const float*)d_in[10];
  float* out = (float*)d_out;

  char* w = (char*)d_ws;
  bf16_t* Aqkv  = (bf16_t*)(w);                       // 3 x [4096][1024] bf16
  bf16_t* WtAll = (bf16_t*)(w + 25165824);            // 4 x [1024][1024] bf16
  bf16_t* Qg    = (bf16_t*)(w + 33554432);            // [4096][1024] bf16
  bf16_t* Kg    = (bf16_t*)(w + 41943040);            // [4096][1024] bf16
  bf16_t* Vt    = (bf16_t*)(w + 50331648);            // [2048][2048] bf16 (per-b, n-major)
  bf16_t* Ctx   = (bf16_t*)(w + 58720256);            // [4096][1024] bf16

  cvt_qkv_kernel<<<2048, 256, 0, stream>>>(q, k, v, Aqkv);
  transpose_w_kernel<<<dim3(32, 32, 4), dim3(32, 8), 0, stream>>>(Wq, Wk, Wv, Wo, WtAll);
  proj_gemm_kernel<<<dim3(16, 32, 3), 256, 0, stream>>>(
      Aqkv, Aqkv + (size_t)MTOT * D_MODEL, Aqkv + 2 * (size_t)MTOT * D_MODEL,
      WtAll, bq, bk, bv, Qg, Kg, Vt);
  attn_kernel<<<dim3(32, 16), 256, 0, stream>>>(Qg, Kg, Vt, Ctx);
  out_gemm_kernel<<<dim3(16, 32), 256, 0, stream>>>(
      Ctx, WtAll + 3 * (size_t)D_MODEL * D_MODEL, bo, out);
}